// Round 6
// baseline (144.505 us; speedup 1.0000x reference)
//
#include <hip/hip_runtime.h>

// SymmetricContraction via symmetrized-basis contraction.
//
// out[n,m,0]   = w0[e,m]*Sum_a S0[a] f_a   + Sum_s w2[e,s,m]*B2_s + Sum_s w4[e,s,m]*B4_s
// out[n,m,1+d] = w1[e,m]*Sum_a S1[a,d] f_a + Sum_s w3[e,s,m]*B3_sd + Sum_s w5[e,s,m]*B5_sd
// where B*_s = Sum_{monomial k} S*[k,s(,d)] * M_k(f), f = feats[n,m,0:9].
//
// R5 -> R6: R2 (LDS), R4 (smem), R5 (smem split) all hit ~42-44 us -> the wall
// is S *broadcast-delivery bandwidth* (every wave re-streams the same ~5-10 KB
// through a shared per-CU port), not latency. Fix: each thread evaluates
// R=4 nodes per S-record fetch (4x less delivery traffic per FLOP), with K
// split 4 ways inside a 512-thread block (4 parts x 128 m) to keep occupancy:
//   part 0: linear + 45 quads + reduction/weights/store epilogue
//   part 1/2/3: cubics [0,55) / [55,110) / [110,165)  (templated -> unrolled)
// Parts 1-3 pass B4[4],B5[6] x4 nodes through LDS; one __syncthreads.
//
// Output row layout (512 floats): [0..127]=d0 per m ; [128+3m+d] = vector part.

#define N_NODES 2048
#define MUL     128
#define NROW    1152
#define NQ      45
#define NC      165
#define KC1     55
#define KC2     110
// float4-unit layout of S: [0,9) linear recs (pad to 12), [12,147) quad recs
// (45 x 3), [147,642) cubic recs (165 x 3).
#define Q4_BASE 12
#define C4_BASE 147
#define S4_TOTAL 642   // float4s -> 10272 bytes (d_ws usage)

// ---------------------------------------------------------------------------
// Kernel 1: build symmetrized basis table S into d_ws. One block, 256 threads.
// ---------------------------------------------------------------------------
__global__ void k_prep(const float* __restrict__ b0, const float* __restrict__ b1,
                       const float* __restrict__ b2, const float* __restrict__ b3,
                       const float* __restrict__ b4, const float* __restrict__ b5,
                       float4* __restrict__ S) {
    const int t = threadIdx.x;
    if (t < 9) {
        S[t] = make_float4(b0[t], b1[t * 3 + 0], b1[t * 3 + 1], b1[t * 3 + 2]);
    } else if (t < Q4_BASE) {
        S[t] = make_float4(0.f, 0.f, 0.f, 0.f);   // pad
    } else if (t < Q4_BASE + NQ) {
        const int k = t - Q4_BASE;
        int a = -1, b = -1, kk = k;
        for (int aa = 0; aa < 9 && a < 0; ++aa) {
            const int cnt = 9 - aa;
            if (kk < cnt) { a = aa; b = aa + kk; } else kk -= cnt;
        }
        const float mult = (a == b) ? 0.5f : 1.0f;
        const int i1 = a * 9 + b, i2 = b * 9 + a;
        float s2[3], s3[6];
        for (int s = 0; s < 3; ++s)
            s2[s] = (b2[i1 * 3 + s] + b2[i2 * 3 + s]) * mult;
        for (int s = 0; s < 2; ++s)
            for (int d = 0; d < 3; ++d)
                s3[s * 3 + d] = (b3[(i1 * 2 + s) * 3 + d] + b3[(i2 * 2 + s) * 3 + d]) * mult;
        S[Q4_BASE + k * 3 + 0] = make_float4(s2[0], s2[1], s2[2], 0.f);
        S[Q4_BASE + k * 3 + 1] = make_float4(s3[0], s3[1], s3[2], s3[3]);
        S[Q4_BASE + k * 3 + 2] = make_float4(s3[4], s3[5], 0.f, 0.f);
    } else if (t < Q4_BASE + NQ + NC) {
        const int k = t - Q4_BASE - NQ;
        int a = -1, b = -1, c = -1, kk = k;
        for (int aa = 0; aa < 9 && a < 0; ++aa)
            for (int bb = aa; bb < 9 && a < 0; ++bb) {
                const int cnt = 9 - bb;
                if (kk < cnt) { a = aa; b = bb; c = bb + kk; } else kk -= cnt;
            }
        const float mult = (a == b && b == c) ? (1.0f / 6.0f)
                         : ((a == b || b == c) ? 0.5f : 1.0f);
        int p[6];
        p[0] = (a * 9 + b) * 9 + c;  p[1] = (a * 9 + c) * 9 + b;
        p[2] = (b * 9 + a) * 9 + c;  p[3] = (b * 9 + c) * 9 + a;
        p[4] = (c * 9 + a) * 9 + b;  p[5] = (c * 9 + b) * 9 + a;
        float s4[4], s5[6];
        for (int s = 0; s < 4; ++s) {
            float v = 0.f;
            for (int j = 0; j < 6; ++j) v += b4[p[j] * 4 + s];
            s4[s] = v * mult;
        }
        for (int s = 0; s < 2; ++s)
            for (int d = 0; d < 3; ++d) {
                float v = 0.f;
                for (int j = 0; j < 6; ++j) v += b5[(p[j] * 2 + s) * 3 + d];
                s5[s * 3 + d] = v * mult;
            }
        S[C4_BASE + k * 3 + 0] = make_float4(s4[0], s4[1], s4[2], s4[3]);
        S[C4_BASE + k * 3 + 1] = make_float4(s5[0], s5[1], s5[2], s5[3]);
        S[C4_BASE + k * 3 + 2] = make_float4(s5[4], s5[5], 0.f, 0.f);
    }
}

// ---------------------------------------------------------------------------
// Kernel 2: evaluate. Block = 512 threads = 4 parts x 128 m; 4 nodes/block.
// ---------------------------------------------------------------------------
typedef float fvec4 __attribute__((ext_vector_type(4)));

#if defined(__HIP_DEVICE_COMPILE__)
typedef const __attribute__((address_space(4))) fvec4* S4cp;

template<int LO, int HI>
__device__ __forceinline__ void do_cubics(S4cp S, const float (&f)[4][9],
                                          float (&B4)[4][4], float (&B5)[4][6]) {
    int kc = 0;
#pragma unroll
    for (int a = 0; a < 9; ++a) {
#pragma unroll
        for (int b = a; b < 9; ++b) {
            float q[4];
#pragma unroll
            for (int i = 0; i < 4; ++i) q[i] = f[i][a] * f[i][b];  // DCE'd if unused
#pragma unroll
            for (int c = b; c < 9; ++c) {
                if (kc >= LO && kc < HI) {   // compile-time folded
                    const fvec4 r0 = S[C4_BASE + kc * 3 + 0];
                    const fvec4 r1 = S[C4_BASE + kc * 3 + 1];
                    const fvec4 r2 = S[C4_BASE + kc * 3 + 2];
#pragma unroll
                    for (int i = 0; i < 4; ++i) {
                        const float tt = q[i] * f[i][c];
                        B4[i][0] += tt * r0.x; B4[i][1] += tt * r0.y;
                        B4[i][2] += tt * r0.z; B4[i][3] += tt * r0.w;
                        B5[i][0] += tt * r1.x; B5[i][1] += tt * r1.y;
                        B5[i][2] += tt * r1.z; B5[i][3] += tt * r1.w;
                        B5[i][4] += tt * r2.x; B5[i][5] += tt * r2.y;
                    }
                }
                ++kc;
            }
        }
    }
}
#endif

__global__ __launch_bounds__(512, 4) void k_eval(
        const float* __restrict__ nf, const int* __restrict__ species,
        const float* __restrict__ w0, const float* __restrict__ w1,
        const float* __restrict__ w2, const float* __restrict__ w3,
        const float* __restrict__ w4, const float* __restrict__ w5,
        const float* __restrict__ Sg, float* __restrict__ out) {
#if defined(__HIP_DEVICE_COMPILE__)
    S4cp S = (S4cp)(unsigned long long)Sg;   // reinterpret into constant AS

    // partials from parts 1..3: [part-1][m][node][12] (10 used, pad to 12 for
    // 16B-aligned chunks; m-stride 48 floats -> 2-way bank aliasing = free)
    __shared__ float red[3][MUL][4][12];     // 73,728 B

    const int tid  = threadIdx.x;
    const int m    = tid & 127;
    const int part = tid >> 7;               // wave-uniform
    const int nb   = blockIdx.x * 4;

    // f for 4 nodes (rows L1-resident: all 4 parts read the same 4 rows)
    float f[4][9];
#pragma unroll
    for (int i = 0; i < 4; ++i) {
        const float* __restrict__ row = nf + (size_t)(nb + i) * NROW;
        f[i][0] = row[m];
#pragma unroll
        for (int j = 0; j < 3; ++j) f[i][1 + j] = row[128 + 3 * m + j];
#pragma unroll
        for (int j = 0; j < 5; ++j) f[i][4 + j] = row[512 + 5 * m + j];
    }

    float A0[4] = {}, A1[4][3] = {};
    float B2[4][3] = {}, B3[4][6] = {};
    float B4[4][4] = {}, B5[4][6] = {};
    float wv0[4], wv1[4], wv2[4][3], wv3[4][2], wv4[4][4], wv5[4][2];

    if (part == 0) {
        // ---- linear ----
#pragma unroll
        for (int a = 0; a < 9; ++a) {
            const fvec4 L = S[a];
#pragma unroll
            for (int i = 0; i < 4; ++i) {
                A0[i]    += L.x * f[i][a];
                A1[i][0] += L.y * f[i][a];
                A1[i][1] += L.z * f[i][a];
                A1[i][2] += L.w * f[i][a];
            }
        }
        // ---- quads ----
        int kq = 0;
#pragma unroll
        for (int a = 0; a < 9; ++a) {
#pragma unroll
            for (int b = a; b < 9; ++b) {
                const fvec4 r0 = S[Q4_BASE + kq * 3 + 0];
                const fvec4 r1 = S[Q4_BASE + kq * 3 + 1];
                const fvec4 r2 = S[Q4_BASE + kq * 3 + 2];
#pragma unroll
                for (int i = 0; i < 4; ++i) {
                    const float q = f[i][a] * f[i][b];
                    B2[i][0] += q * r0.x; B2[i][1] += q * r0.y; B2[i][2] += q * r0.z;
                    B3[i][0] += q * r1.x; B3[i][1] += q * r1.y; B3[i][2] += q * r1.z;
                    B3[i][3] += q * r1.w; B3[i][4] += q * r2.x; B3[i][5] += q * r2.y;
                }
                ++kq;
            }
        }
        // prefetch per-(e,m) weights before the barrier (overlap latency)
#pragma unroll
        for (int i = 0; i < 4; ++i) {
            const int e = species[nb + i];
            wv0[i] = w0[e * MUL + m];
            wv1[i] = w1[e * MUL + m];
#pragma unroll
            for (int s = 0; s < 3; ++s) wv2[i][s] = w2[(e * 3 + s) * MUL + m];
#pragma unroll
            for (int s = 0; s < 2; ++s) wv3[i][s] = w3[(e * 2 + s) * MUL + m];
#pragma unroll
            for (int s = 0; s < 4; ++s) wv4[i][s] = w4[(e * 4 + s) * MUL + m];
#pragma unroll
            for (int s = 0; s < 2; ++s) wv5[i][s] = w5[(e * 2 + s) * MUL + m];
        }
    } else {
        if (part == 1)      do_cubics<0,   KC1>(S, f, B4, B5);
        else if (part == 2) do_cubics<KC1, KC2>(S, f, B4, B5);
        else                do_cubics<KC2, NC >(S, f, B4, B5);
        float* __restrict__ dst = &red[part - 1][m][0][0];
#pragma unroll
        for (int i = 0; i < 4; ++i) {
#pragma unroll
            for (int j = 0; j < 4; ++j) dst[i * 12 + j] = B4[i][j];
#pragma unroll
            for (int j = 0; j < 6; ++j) dst[i * 12 + 4 + j] = B5[i][j];
        }
    }

    __syncthreads();

    if (part == 0) {
        // reduce parts 1..3
#pragma unroll
        for (int p = 0; p < 3; ++p) {
            const float* __restrict__ src = &red[p][m][0][0];
#pragma unroll
            for (int i = 0; i < 4; ++i) {
#pragma unroll
                for (int j = 0; j < 4; ++j) B4[i][j] += src[i * 12 + j];
#pragma unroll
                for (int j = 0; j < 6; ++j) B5[i][j] += src[i * 12 + 4 + j];
            }
        }
        // weights + store
#pragma unroll
        for (int i = 0; i < 4; ++i) {
            float* __restrict__ orow = out + (size_t)(nb + i) * 512;
            orow[m] = wv0[i] * A0[i]
                    + wv2[i][0] * B2[i][0] + wv2[i][1] * B2[i][1] + wv2[i][2] * B2[i][2]
                    + wv4[i][0] * B4[i][0] + wv4[i][1] * B4[i][1]
                    + wv4[i][2] * B4[i][2] + wv4[i][3] * B4[i][3];
#pragma unroll
            for (int d = 0; d < 3; ++d) {
                orow[128 + 3 * m + d] = wv1[i] * A1[i][d]
                                      + wv3[i][0] * B3[i][d] + wv3[i][1] * B3[i][3 + d]
                                      + wv5[i][0] * B5[i][d] + wv5[i][1] * B5[i][3 + d];
            }
        }
    }
#endif  // __HIP_DEVICE_COMPILE__
}

// ---------------------------------------------------------------------------
extern "C" void kernel_launch(void* const* d_in, const int* in_sizes, int n_in,
                              void* d_out, int out_size, void* d_ws, size_t ws_size,
                              hipStream_t stream) {
    const float* nf      = (const float*)d_in[0];
    const int*   species = (const int*)d_in[1];
    const float* b0 = (const float*)d_in[2];  const float* w0 = (const float*)d_in[3];
    const float* b1 = (const float*)d_in[4];  const float* w1 = (const float*)d_in[5];
    const float* b2 = (const float*)d_in[6];  const float* w2 = (const float*)d_in[7];
    const float* b3 = (const float*)d_in[8];  const float* w3 = (const float*)d_in[9];
    const float* b4 = (const float*)d_in[10]; const float* w4 = (const float*)d_in[11];
    const float* b5 = (const float*)d_in[12]; const float* w5 = (const float*)d_in[13];
    float* out = (float*)d_out;

    float4* S = (float4*)d_ws;   // 642 float4 = 10,272 bytes only

    hipLaunchKernelGGL(k_prep, dim3(1), dim3(256), 0, stream,
                       b0, b1, b2, b3, b4, b5, S);
    // 512 blocks x 512 threads; block = 4 nodes, 128 m x 4 K-parts
    hipLaunchKernelGGL(k_eval, dim3(N_NODES / 4), dim3(512), 0, stream,
                       nf, species, w0, w1, w2, w3, w4, w5,
                       (const float*)S, out);
}

// Round 7
// 110.382 us; speedup vs baseline: 1.3091x; 1.3091x over previous
//
#include <hip/hip_runtime.h>

// SymmetricContraction via symmetrized-basis contraction.
//
// out[n,m,0]   = w0[e,m]*Sum_a S0[a] f_a   + Sum_s w2[e,s,m]*B2_s + Sum_s w4[e,s,m]*B4_s
// out[n,m,1+d] = w1[e,m]*Sum_a S1[a,d] f_a + Sum_s w3[e,s,m]*B3_sd + Sum_s w5[e,s,m]*B5_sd
// where B*_s = Sum_{monomial k} S*[k,s(,d)] * M_k(f), f = feats[n,m,0:9].
//
// R6 -> R7 post-mortem: R6's __launch_bounds__(512,4) clamped VGPR to 64 ->
// massive scratch spills (WRITE_SIZE 117 MB, FETCH 35 MB => 55 us memory-bound
// on spill traffic), plus red[][] lane-stride 48 -> 2-bank/32-way LDS conflicts
// (2.48M). Fixes, keeping the R=4-nodes-per-thread / 4-way-K-split plan:
//   1. plain __launch_bounds__(512): no VGPR clamp, no spills. LDS 60 KB
//      already limits to 2 blocks/CU = 16 waves/CU (the occupancy we wanted).
//   2. reduction buffer transposed to red[3][10][4][128]: lane stride 1,
//      conflict-free.
// Parts: part0 = linear + 45 quads + epilogue; parts 1/2/3 = 55 cubics each.
//
// Output row layout (512 floats): [0..127]=d0 per m ; [128+3m+d] = vector part.

#define N_NODES 2048
#define MUL     128
#define NROW    1152
#define NQ      45
#define NC      165
#define KC1     55
#define KC2     110
// float4-unit layout of S: [0,9) linear recs (pad to 12), [12,147) quad recs
// (45 x 3), [147,642) cubic recs (165 x 3).
#define Q4_BASE 12
#define C4_BASE 147
#define S4_TOTAL 642   // float4s -> 10272 bytes (d_ws usage)

// ---------------------------------------------------------------------------
// Kernel 1: build symmetrized basis table S into d_ws. One block, 256 threads.
// ---------------------------------------------------------------------------
__global__ void k_prep(const float* __restrict__ b0, const float* __restrict__ b1,
                       const float* __restrict__ b2, const float* __restrict__ b3,
                       const float* __restrict__ b4, const float* __restrict__ b5,
                       float4* __restrict__ S) {
    const int t = threadIdx.x;
    if (t < 9) {
        S[t] = make_float4(b0[t], b1[t * 3 + 0], b1[t * 3 + 1], b1[t * 3 + 2]);
    } else if (t < Q4_BASE) {
        S[t] = make_float4(0.f, 0.f, 0.f, 0.f);   // pad
    } else if (t < Q4_BASE + NQ) {
        const int k = t - Q4_BASE;
        int a = -1, b = -1, kk = k;
        for (int aa = 0; aa < 9 && a < 0; ++aa) {
            const int cnt = 9 - aa;
            if (kk < cnt) { a = aa; b = aa + kk; } else kk -= cnt;
        }
        const float mult = (a == b) ? 0.5f : 1.0f;
        const int i1 = a * 9 + b, i2 = b * 9 + a;
        float s2[3], s3[6];
        for (int s = 0; s < 3; ++s)
            s2[s] = (b2[i1 * 3 + s] + b2[i2 * 3 + s]) * mult;
        for (int s = 0; s < 2; ++s)
            for (int d = 0; d < 3; ++d)
                s3[s * 3 + d] = (b3[(i1 * 2 + s) * 3 + d] + b3[(i2 * 2 + s) * 3 + d]) * mult;
        S[Q4_BASE + k * 3 + 0] = make_float4(s2[0], s2[1], s2[2], 0.f);
        S[Q4_BASE + k * 3 + 1] = make_float4(s3[0], s3[1], s3[2], s3[3]);
        S[Q4_BASE + k * 3 + 2] = make_float4(s3[4], s3[5], 0.f, 0.f);
    } else if (t < Q4_BASE + NQ + NC) {
        const int k = t - Q4_BASE - NQ;
        int a = -1, b = -1, c = -1, kk = k;
        for (int aa = 0; aa < 9 && a < 0; ++aa)
            for (int bb = aa; bb < 9 && a < 0; ++bb) {
                const int cnt = 9 - bb;
                if (kk < cnt) { a = aa; b = bb; c = bb + kk; } else kk -= cnt;
            }
        const float mult = (a == b && b == c) ? (1.0f / 6.0f)
                         : ((a == b || b == c) ? 0.5f : 1.0f);
        int p[6];
        p[0] = (a * 9 + b) * 9 + c;  p[1] = (a * 9 + c) * 9 + b;
        p[2] = (b * 9 + a) * 9 + c;  p[3] = (b * 9 + c) * 9 + a;
        p[4] = (c * 9 + a) * 9 + b;  p[5] = (c * 9 + b) * 9 + a;
        float s4[4], s5[6];
        for (int s = 0; s < 4; ++s) {
            float v = 0.f;
            for (int j = 0; j < 6; ++j) v += b4[p[j] * 4 + s];
            s4[s] = v * mult;
        }
        for (int s = 0; s < 2; ++s)
            for (int d = 0; d < 3; ++d) {
                float v = 0.f;
                for (int j = 0; j < 6; ++j) v += b5[(p[j] * 2 + s) * 3 + d];
                s5[s * 3 + d] = v * mult;
            }
        S[C4_BASE + k * 3 + 0] = make_float4(s4[0], s4[1], s4[2], s4[3]);
        S[C4_BASE + k * 3 + 1] = make_float4(s5[0], s5[1], s5[2], s5[3]);
        S[C4_BASE + k * 3 + 2] = make_float4(s5[4], s5[5], 0.f, 0.f);
    }
}

// ---------------------------------------------------------------------------
// Kernel 2: evaluate. Block = 512 threads = 4 parts x 128 m; 4 nodes/block.
// ---------------------------------------------------------------------------
typedef float fvec4 __attribute__((ext_vector_type(4)));

#if defined(__HIP_DEVICE_COMPILE__)
typedef const __attribute__((address_space(4))) fvec4* S4cp;

template<int LO, int HI>
__device__ __forceinline__ void do_cubics(S4cp S, const float (&f)[4][9],
                                          float (&B4)[4][4], float (&B5)[4][6]) {
    int kc = 0;
#pragma unroll
    for (int a = 0; a < 9; ++a) {
#pragma unroll
        for (int b = a; b < 9; ++b) {
            float q[4];
#pragma unroll
            for (int i = 0; i < 4; ++i) q[i] = f[i][a] * f[i][b];  // DCE'd if unused
#pragma unroll
            for (int c = b; c < 9; ++c) {
                if (kc >= LO && kc < HI) {   // compile-time folded
                    const fvec4 r0 = S[C4_BASE + kc * 3 + 0];
                    const fvec4 r1 = S[C4_BASE + kc * 3 + 1];
                    const fvec4 r2 = S[C4_BASE + kc * 3 + 2];
#pragma unroll
                    for (int i = 0; i < 4; ++i) {
                        const float tt = q[i] * f[i][c];
                        B4[i][0] += tt * r0.x; B4[i][1] += tt * r0.y;
                        B4[i][2] += tt * r0.z; B4[i][3] += tt * r0.w;
                        B5[i][0] += tt * r1.x; B5[i][1] += tt * r1.y;
                        B5[i][2] += tt * r1.z; B5[i][3] += tt * r1.w;
                        B5[i][4] += tt * r2.x; B5[i][5] += tt * r2.y;
                    }
                }
                ++kc;
            }
        }
    }
}
#endif

__global__ __launch_bounds__(512) void k_eval(
        const float* __restrict__ nf, const int* __restrict__ species,
        const float* __restrict__ w0, const float* __restrict__ w1,
        const float* __restrict__ w2, const float* __restrict__ w3,
        const float* __restrict__ w4, const float* __restrict__ w5,
        const float* __restrict__ Sg, float* __restrict__ out) {
#if defined(__HIP_DEVICE_COMPILE__)
    S4cp S = (S4cp)(unsigned long long)Sg;   // reinterpret into constant AS

    // partials from parts 1..3: [part-1][slot(0..9)][node][m]
    // lane index m is the fastest dim -> stride-1 -> conflict-free.
    __shared__ float red[3][10][4][MUL];     // 61,440 B -> 2 blocks/CU

    const int tid  = threadIdx.x;
    const int m    = tid & 127;
    const int part = tid >> 7;               // wave-uniform
    const int nb   = blockIdx.x * 4;

    // f for 4 nodes (all 4 parts read the same rows -> L1 broadcast)
    float f[4][9];
#pragma unroll
    for (int i = 0; i < 4; ++i) {
        const float* __restrict__ row = nf + (size_t)(nb + i) * NROW;
        f[i][0] = row[m];
#pragma unroll
        for (int j = 0; j < 3; ++j) f[i][1 + j] = row[128 + 3 * m + j];
#pragma unroll
        for (int j = 0; j < 5; ++j) f[i][4 + j] = row[512 + 5 * m + j];
    }

    float A0[4] = {}, A1[4][3] = {};
    float B2[4][3] = {}, B3[4][6] = {};
    float B4[4][4] = {}, B5[4][6] = {};

    if (part == 0) {
        // ---- linear ----
#pragma unroll
        for (int a = 0; a < 9; ++a) {
            const fvec4 L = S[a];
#pragma unroll
            for (int i = 0; i < 4; ++i) {
                A0[i]    += L.x * f[i][a];
                A1[i][0] += L.y * f[i][a];
                A1[i][1] += L.z * f[i][a];
                A1[i][2] += L.w * f[i][a];
            }
        }
        // ---- quads ----
        int kq = 0;
#pragma unroll
        for (int a = 0; a < 9; ++a) {
#pragma unroll
            for (int b = a; b < 9; ++b) {
                const fvec4 r0 = S[Q4_BASE + kq * 3 + 0];
                const fvec4 r1 = S[Q4_BASE + kq * 3 + 1];
                const fvec4 r2 = S[Q4_BASE + kq * 3 + 2];
#pragma unroll
                for (int i = 0; i < 4; ++i) {
                    const float q = f[i][a] * f[i][b];
                    B2[i][0] += q * r0.x; B2[i][1] += q * r0.y; B2[i][2] += q * r0.z;
                    B3[i][0] += q * r1.x; B3[i][1] += q * r1.y; B3[i][2] += q * r1.z;
                    B3[i][3] += q * r1.w; B3[i][4] += q * r2.x; B3[i][5] += q * r2.y;
                }
                ++kq;
            }
        }
    } else {
        if (part == 1)      do_cubics<0,   KC1>(S, f, B4, B5);
        else if (part == 2) do_cubics<KC1, KC2>(S, f, B4, B5);
        else                do_cubics<KC2, NC >(S, f, B4, B5);
#pragma unroll
        for (int i = 0; i < 4; ++i) {
#pragma unroll
            for (int j = 0; j < 4; ++j) red[part - 1][j][i][m] = B4[i][j];
#pragma unroll
            for (int j = 0; j < 6; ++j) red[part - 1][4 + j][i][m] = B5[i][j];
        }
    }

    __syncthreads();

    if (part == 0) {
        // reduce parts 1..3 (stride-1 lane access, conflict-free)
#pragma unroll
        for (int p = 0; p < 3; ++p) {
#pragma unroll
            for (int i = 0; i < 4; ++i) {
#pragma unroll
                for (int j = 0; j < 4; ++j) B4[i][j] += red[p][j][i][m];
#pragma unroll
                for (int j = 0; j < 6; ++j) B5[i][j] += red[p][4 + j][i][m];
            }
        }
        // weights + store (loaded after barrier to keep pre-barrier regs low)
#pragma unroll
        for (int i = 0; i < 4; ++i) {
            const int e = species[nb + i];
            const float wv0 = w0[e * MUL + m];
            const float wv1 = w1[e * MUL + m];
            float wv2[3], wv3[2], wv4[4], wv5[2];
#pragma unroll
            for (int s = 0; s < 3; ++s) wv2[s] = w2[(e * 3 + s) * MUL + m];
#pragma unroll
            for (int s = 0; s < 2; ++s) wv3[s] = w3[(e * 2 + s) * MUL + m];
#pragma unroll
            for (int s = 0; s < 4; ++s) wv4[s] = w4[(e * 4 + s) * MUL + m];
#pragma unroll
            for (int s = 0; s < 2; ++s) wv5[s] = w5[(e * 2 + s) * MUL + m];

            float* __restrict__ orow = out + (size_t)(nb + i) * 512;
            orow[m] = wv0 * A0[i]
                    + wv2[0] * B2[i][0] + wv2[1] * B2[i][1] + wv2[2] * B2[i][2]
                    + wv4[0] * B4[i][0] + wv4[1] * B4[i][1]
                    + wv4[2] * B4[i][2] + wv4[3] * B4[i][3];
#pragma unroll
            for (int d = 0; d < 3; ++d) {
                orow[128 + 3 * m + d] = wv1 * A1[i][d]
                                      + wv3[0] * B3[i][d] + wv3[1] * B3[i][3 + d]
                                      + wv5[0] * B5[i][d] + wv5[1] * B5[i][3 + d];
            }
        }
    }
#endif  // __HIP_DEVICE_COMPILE__
}

// ---------------------------------------------------------------------------
extern "C" void kernel_launch(void* const* d_in, const int* in_sizes, int n_in,
                              void* d_out, int out_size, void* d_ws, size_t ws_size,
                              hipStream_t stream) {
    const float* nf      = (const float*)d_in[0];
    const int*   species = (const int*)d_in[1];
    const float* b0 = (const float*)d_in[2];  const float* w0 = (const float*)d_in[3];
    const float* b1 = (const float*)d_in[4];  const float* w1 = (const float*)d_in[5];
    const float* b2 = (const float*)d_in[6];  const float* w2 = (const float*)d_in[7];
    const float* b3 = (const float*)d_in[8];  const float* w3 = (const float*)d_in[9];
    const float* b4 = (const float*)d_in[10]; const float* w4 = (const float*)d_in[11];
    const float* b5 = (const float*)d_in[12]; const float* w5 = (const float*)d_in[13];
    float* out = (float*)d_out;

    float4* S = (float4*)d_ws;   // 642 float4 = 10,272 bytes only

    hipLaunchKernelGGL(k_prep, dim3(1), dim3(256), 0, stream,
                       b0, b1, b2, b3, b4, b5, S);
    // 512 blocks x 512 threads; block = 4 nodes, 128 m x 4 K-parts
    hipLaunchKernelGGL(k_eval, dim3(N_NODES / 4), dim3(512), 0, stream,
                       nf, species, w0, w1, w2, w3, w4, w5,
                       (const float*)S, out);
}